// Round 3
// baseline (434.890 us; speedup 1.0000x reference)
//
#include <hip/hip_runtime.h>

// Problem constants
#define NPTS  32768
#define KNB   16
#define CH    128
#define INNER 512
#define EPS   1e-5f

// Workspace layout (float offsets): M[128*128], stats[256] (sum|sumsq), coef[256]
#define WS_M     0
#define WS_STATS 16384
#define WS_COEF  16640

// ---------------------------------------------------------------------------
// Kernel 1: M = Wv @ Wo  (128x512 @ 512x128 -> 128x128); block 0 also zeroes
// the stats accumulator (ws is poisoned 0xAA by the harness each iteration).
// ---------------------------------------------------------------------------
__global__ __launch_bounds__(256) void k_wvwo(const float* __restrict__ Wv,
                                              const float* __restrict__ Wo,
                                              float* __restrict__ M,
                                              float* __restrict__ stats) {
    int t  = threadIdx.x;
    if (blockIdx.x == 0) stats[t] = 0.f;     // 256 floats
    int id = blockIdx.x * 256 + t;           // 0..16383
    int c  = id >> 7;
    int cp = id & 127;
    const float* wvr = Wv + c * INNER;
    float acc = 0.f;
#pragma unroll 8
    for (int i = 0; i < INNER; ++i)
        acc = fmaf(wvr[i], Wo[i * CH + cp], acc);
    M[c * CH + cp] = acc;
}

// ---------------------------------------------------------------------------
// Kernel 2 (main): per block of 32 points:
//   phase 1: hs[p][c] = sum_k h[n,k,c]      (streams 256 MB, coalesced f4)
//   phase 2: y[p][c'] = hs[p][:] @ M[:,c']  (M rows L1/L2-hot)
//   epilogue: y -> d_out (unnormalized), per-channel sum/sumsq block-reduced
//             then ONE device-scope atomicAdd per thread into stats[256].
// ---------------------------------------------------------------------------
__global__ __launch_bounds__(256) void k_main(const float* __restrict__ h,
                                              const float* __restrict__ Mg,
                                              float* __restrict__ y,
                                              float* __restrict__ stats) {
    __shared__ float4 hs4[32 * 32];      // hs[32 pts][128 ch] as float4
    __shared__ float  red[4][2][128];    // cross-wave stat reduce

    const int t  = threadIdx.x;
    const int n0 = blockIdx.x * 32;
    const float4* __restrict__ h4 = (const float4*)h;

    // ---- phase 1: k-sum ----
#pragma unroll 2
    for (int j = 0; j < 4; ++j) {
        int pi = t + 256 * j;
        int p  = pi >> 5;          // point within block
        int c4 = pi & 31;          // channel-quad
        size_t base = (size_t)(n0 + p) * (KNB * 32) + c4;   // float4 index
        float4 a = h4[base];
#pragma unroll
        for (int k = 1; k < KNB; ++k) {
            float4 v = h4[base + (size_t)k * 32];
            a.x += v.x; a.y += v.y; a.z += v.z; a.w += v.w;
        }
        hs4[p * 32 + c4] = a;
    }
    __syncthreads();

    // ---- phase 2: GEMV  y = hs @ M ----
    const int w  = t >> 6;     // wave 0..3
    const int l  = t & 63;     // lane
    const int p0 = w * 8;      // 8 points per wave
    float acc0[8] = {0,0,0,0,0,0,0,0};   // channel l
    float acc1[8] = {0,0,0,0,0,0,0,0};   // channel l+64

    for (int cc = 0; cc < 32; ++cc) {
        const int c = 4 * cc;
        float m00 = Mg[(c + 0) * CH + l];
        float m01 = Mg[(c + 1) * CH + l];
        float m02 = Mg[(c + 2) * CH + l];
        float m03 = Mg[(c + 3) * CH + l];
        float m10 = Mg[(c + 0) * CH + 64 + l];
        float m11 = Mg[(c + 1) * CH + 64 + l];
        float m12 = Mg[(c + 2) * CH + 64 + l];
        float m13 = Mg[(c + 3) * CH + 64 + l];
#pragma unroll
        for (int p = 0; p < 8; ++p) {
            float4 hv = hs4[(p0 + p) * 32 + cc];   // LDS broadcast (free)
            acc0[p] = fmaf(hv.x, m00, acc0[p]);
            acc0[p] = fmaf(hv.y, m01, acc0[p]);
            acc0[p] = fmaf(hv.z, m02, acc0[p]);
            acc0[p] = fmaf(hv.w, m03, acc0[p]);
            acc1[p] = fmaf(hv.x, m10, acc1[p]);
            acc1[p] = fmaf(hv.y, m11, acc1[p]);
            acc1[p] = fmaf(hv.z, m12, acc1[p]);
            acc1[p] = fmaf(hv.w, m13, acc1[p]);
        }
    }

    // ---- epilogue: write y, block-reduce stats, one atomic per thread ----
    float s0 = 0.f, s1 = 0.f, q0 = 0.f, q1 = 0.f;
#pragma unroll
    for (int p = 0; p < 8; ++p) {
        size_t row = (size_t)(n0 + p0 + p) * CH;
        y[row + l]      = acc0[p];
        y[row + 64 + l] = acc1[p];
        s0 += acc0[p];  q0 = fmaf(acc0[p], acc0[p], q0);
        s1 += acc1[p];  q1 = fmaf(acc1[p], acc1[p], q1);
    }
    red[w][0][l]      = s0;
    red[w][0][64 + l] = s1;
    red[w][1][l]      = q0;
    red[w][1][64 + l] = q1;
    __syncthreads();
    {
        int s = t >> 7, c = t & 127;
        float v = red[0][s][c] + red[1][s][c] + red[2][s][c] + red[3][s][c];
        atomicAdd(&stats[t], v);   // device-scope by default on gfx950
    }
}

// ---------------------------------------------------------------------------
// Kernel 3: BN coefficients from final stats (1 block, 128 threads)
//   coef[c]     = gamma[c] * rsqrt(var+eps)
//   coef[128+c] = beta[c] - mu * coef[c]
// ---------------------------------------------------------------------------
__global__ __launch_bounds__(128) void k_coef(const float* __restrict__ stats,
                                              const float* __restrict__ gamma,
                                              const float* __restrict__ beta,
                                              float* __restrict__ coef) {
    int c = threadIdx.x;
    float S  = stats[c];
    float Q  = stats[128 + c];
    float mu = S * (1.f / NPTS);
    float var = Q * (1.f / NPTS) - mu * mu;   // biased variance
    float rs = rsqrtf(var + EPS);
    float a  = gamma[c] * rs;
    coef[c]       = a;
    coef[128 + c] = beta[c] - mu * a;
}

// ---------------------------------------------------------------------------
// Kernel 4: in-place normalize + ReLU on d_out (float4; y is L3-hot)
// ---------------------------------------------------------------------------
__global__ __launch_bounds__(256) void k_norm(float* __restrict__ y,
                                              const float* __restrict__ coef) {
    int gid = blockIdx.x * 256 + threadIdx.x;       // 262144 threads
    float4* y4 = (float4*)y;
    const float4* c4 = (const float4*)coef;
    int lc = gid & 31;                              // same channel-quad every iter
    float4 a = c4[lc];
    float4 b = c4[32 + lc];
#pragma unroll
    for (int i = 0; i < 4; ++i) {
        size_t idx = (size_t)gid + (size_t)i * 262144;
        float4 v = y4[idx];
        v.x = fmaxf(0.f, fmaf(v.x, a.x, b.x));
        v.y = fmaxf(0.f, fmaf(v.y, a.y, b.y));
        v.z = fmaxf(0.f, fmaf(v.z, a.z, b.z));
        v.w = fmaxf(0.f, fmaf(v.w, a.w, b.w));
        y4[idx] = v;
    }
}

// ---------------------------------------------------------------------------
extern "C" void kernel_launch(void* const* d_in, const int* in_sizes, int n_in,
                              void* d_out, int out_size, void* d_ws, size_t ws_size,
                              hipStream_t stream) {
    // inputs: h, x, Wq, Wk, Wv, Wo, bo, gamma, beta
    const float* h     = (const float*)d_in[0];
    const float* Wv    = (const float*)d_in[4];
    const float* Wo    = (const float*)d_in[5];
    const float* gamma = (const float*)d_in[7];
    const float* beta  = (const float*)d_in[8];
    // x, Wq, Wk dead (softmax over singleton dim == 1); bo cancels in BN.

    float* out   = (float*)d_out;
    float* ws    = (float*)d_ws;
    float* M     = ws + WS_M;
    float* stats = ws + WS_STATS;
    float* coef  = ws + WS_COEF;

    k_wvwo<<<64,   256, 0, stream>>>(Wv, Wo, M, stats);
    k_main<<<1024, 256, 0, stream>>>(h, M, out, stats);
    k_coef<<<1,    128, 0, stream>>>(stats, gamma, beta, coef);
    k_norm<<<1024, 256, 0, stream>>>(out, coef);
}

// Round 5
// 409.052 us; speedup vs baseline: 1.0632x; 1.0632x over previous
//
#include <hip/hip_runtime.h>

// Problem constants
#define NPTS  32768
#define KNB   16
#define CH    128
#define INNER 512
#define EPS   1e-5f

// Workspace layout (float offsets): M[128*128], stats[256] (sum|sumsq)
#define WS_M     0
#define WS_STATS 16384

// Native vector type — __builtin_nontemporal_load requires a real vector,
// not HIP's struct-wrapped float4.
typedef float f4 __attribute__((ext_vector_type(4)));

// ---------------------------------------------------------------------------
// Kernel 1: M = Wv @ Wo  (128x512 @ 512x128 -> 128x128); block 0 also zeroes
// the stats accumulator (ws is poisoned 0xAA by the harness each iteration).
// 4-way split accumulators: only 1 wave/SIMD resident at 64 blocks, so the
// single-acc version was FMA-latency-bound (512 dependent fmas).
// ---------------------------------------------------------------------------
__global__ __launch_bounds__(256) void k_wvwo(const float* __restrict__ Wv,
                                              const float* __restrict__ Wo,
                                              float* __restrict__ M,
                                              float* __restrict__ stats) {
    int t  = threadIdx.x;
    if (blockIdx.x == 0) stats[t] = 0.f;     // 256 floats
    int id = blockIdx.x * 256 + t;           // 0..16383
    int c  = id >> 7;
    int cp = id & 127;
    const float* wvr = Wv + c * INNER;
    float a0 = 0.f, a1 = 0.f, a2 = 0.f, a3 = 0.f;
#pragma unroll 4
    for (int i = 0; i < INNER; i += 4) {
        a0 = fmaf(wvr[i + 0], Wo[(i + 0) * CH + cp], a0);
        a1 = fmaf(wvr[i + 1], Wo[(i + 1) * CH + cp], a1);
        a2 = fmaf(wvr[i + 2], Wo[(i + 2) * CH + cp], a2);
        a3 = fmaf(wvr[i + 3], Wo[(i + 3) * CH + cp], a3);
    }
    M[c * CH + cp] = (a0 + a1) + (a2 + a3);
}

// ---------------------------------------------------------------------------
// Kernel 2 (main): per block of 32 points:
//   phase 1: hs[p][c] = sum_k h[n,k,c]   (streams 256 MB, coalesced 16B,
//            NON-TEMPORAL: h is touched once; keep y/M resident in L2/L3)
//   phase 2: y[p][c'] = hs[p][:] @ M[:,c']   (M rows L1/L2-hot)
//   epilogue: y -> d_out (unnormalized), per-channel sum/sumsq block-reduced,
//             then ONE device-scope atomicAdd per thread into stats[256].
// ---------------------------------------------------------------------------
__global__ __launch_bounds__(256) void k_main(const float* __restrict__ h,
                                              const float* __restrict__ Mg,
                                              float* __restrict__ y,
                                              float* __restrict__ stats) {
    __shared__ f4    hs4[32 * 32];       // hs[32 pts][128 ch] as float4
    __shared__ float red[4][2][128];     // cross-wave stat reduce

    const int t  = threadIdx.x;
    const int n0 = blockIdx.x * 32;
    const f4* __restrict__ h4 = (const f4*)h;

    // ---- phase 1: k-sum ----
#pragma unroll 2
    for (int j = 0; j < 4; ++j) {
        int pi = t + 256 * j;
        int p  = pi >> 5;          // point within block
        int c4 = pi & 31;          // channel-quad
        size_t base = (size_t)(n0 + p) * (KNB * 32) + c4;   // float4 index
        f4 a = __builtin_nontemporal_load(&h4[base]);
#pragma unroll
        for (int k = 1; k < KNB; ++k) {
            f4 v = __builtin_nontemporal_load(&h4[base + (size_t)k * 32]);
            a += v;
        }
        hs4[p * 32 + c4] = a;
    }
    __syncthreads();

    // ---- phase 2: GEMV  y = hs @ M ----
    const int w  = t >> 6;     // wave 0..3
    const int l  = t & 63;     // lane
    const int p0 = w * 8;      // 8 points per wave
    float acc0[8] = {0,0,0,0,0,0,0,0};   // channel l
    float acc1[8] = {0,0,0,0,0,0,0,0};   // channel l+64

    for (int cc = 0; cc < 32; ++cc) {
        const int c = 4 * cc;
        float m00 = Mg[(c + 0) * CH + l];
        float m01 = Mg[(c + 1) * CH + l];
        float m02 = Mg[(c + 2) * CH + l];
        float m03 = Mg[(c + 3) * CH + l];
        float m10 = Mg[(c + 0) * CH + 64 + l];
        float m11 = Mg[(c + 1) * CH + 64 + l];
        float m12 = Mg[(c + 2) * CH + 64 + l];
        float m13 = Mg[(c + 3) * CH + 64 + l];
#pragma unroll
        for (int p = 0; p < 8; ++p) {
            f4 hv = hs4[(p0 + p) * 32 + cc];   // LDS broadcast (free)
            acc0[p] = fmaf(hv.x, m00, acc0[p]);
            acc0[p] = fmaf(hv.y, m01, acc0[p]);
            acc0[p] = fmaf(hv.z, m02, acc0[p]);
            acc0[p] = fmaf(hv.w, m03, acc0[p]);
            acc1[p] = fmaf(hv.x, m10, acc1[p]);
            acc1[p] = fmaf(hv.y, m11, acc1[p]);
            acc1[p] = fmaf(hv.z, m12, acc1[p]);
            acc1[p] = fmaf(hv.w, m13, acc1[p]);
        }
    }

    // ---- epilogue: write y, block-reduce stats, one atomic per thread ----
    float s0 = 0.f, s1 = 0.f, q0 = 0.f, q1 = 0.f;
#pragma unroll
    for (int p = 0; p < 8; ++p) {
        size_t row = (size_t)(n0 + p0 + p) * CH;
        y[row + l]      = acc0[p];
        y[row + 64 + l] = acc1[p];
        s0 += acc0[p];  q0 = fmaf(acc0[p], acc0[p], q0);
        s1 += acc1[p];  q1 = fmaf(acc1[p], acc1[p], q1);
    }
    red[w][0][l]      = s0;
    red[w][0][64 + l] = s1;
    red[w][1][l]      = q0;
    red[w][1][64 + l] = q1;
    __syncthreads();
    {
        int s = t >> 7, c = t & 127;
        float v = red[0][s][c] + red[1][s][c] + red[2][s][c] + red[3][s][c];
        atomicAdd(&stats[t], v);   // device-scope by default on gfx950
    }
}

// ---------------------------------------------------------------------------
// Kernel 3: normalize + ReLU in-place on d_out. Every block redundantly
// computes the BN coefficients from stats[256] (L2-hot, ~200 cyc) — removes
// the separate latency-bound k_coef launch.
// ---------------------------------------------------------------------------
__global__ __launch_bounds__(256) void k_norm(float* __restrict__ y,
                                              const float* __restrict__ stats,
                                              const float* __restrict__ gamma,
                                              const float* __restrict__ beta) {
    __shared__ float sa[128], sb[128];
    int t = threadIdx.x;
    if (t < 128) {
        float S  = stats[t];
        float Q  = stats[128 + t];
        float mu = S * (1.f / NPTS);
        float var = Q * (1.f / NPTS) - mu * mu;   // biased variance
        float a  = gamma[t] * rsqrtf(var + EPS);
        sa[t] = a;
        sb[t] = beta[t] - mu * a;
    }
    __syncthreads();

    int gid = blockIdx.x * 256 + t;                 // 262144 threads
    f4* y4 = (f4*)y;
    int c0 = (gid & 31) * 4;                        // channel-quad, same every iter
    f4 a = { sa[c0], sa[c0 + 1], sa[c0 + 2], sa[c0 + 3] };
    f4 b = { sb[c0], sb[c0 + 1], sb[c0 + 2], sb[c0 + 3] };
#pragma unroll
    for (int i = 0; i < 4; ++i) {
        size_t idx = (size_t)gid + (size_t)i * 262144;
        f4 v = y4[idx];
        v.x = fmaxf(0.f, fmaf(v.x, a.x, b.x));
        v.y = fmaxf(0.f, fmaf(v.y, a.y, b.y));
        v.z = fmaxf(0.f, fmaf(v.z, a.z, b.z));
        v.w = fmaxf(0.f, fmaf(v.w, a.w, b.w));
        y4[idx] = v;
    }
}

// ---------------------------------------------------------------------------
extern "C" void kernel_launch(void* const* d_in, const int* in_sizes, int n_in,
                              void* d_out, int out_size, void* d_ws, size_t ws_size,
                              hipStream_t stream) {
    // inputs: h, x, Wq, Wk, Wv, Wo, bo, gamma, beta
    const float* h     = (const float*)d_in[0];
    const float* Wv    = (const float*)d_in[4];
    const float* Wo    = (const float*)d_in[5];
    const float* gamma = (const float*)d_in[7];
    const float* beta  = (const float*)d_in[8];
    // x, Wq, Wk dead (softmax over singleton dim == 1); bo cancels in BN.

    float* out   = (float*)d_out;
    float* ws    = (float*)d_ws;
    float* M     = ws + WS_M;
    float* stats = ws + WS_STATS;

    k_wvwo<<<64,   256, 0, stream>>>(Wv, Wo, M, stats);
    k_main<<<1024, 256, 0, stream>>>(h, M, out, stats);
    k_norm<<<1024, 256, 0, stream>>>(out, stats, gamma, beta);
}